// Round 2
// baseline (701.353 us; speedup 1.0000x reference)
//
#include <hip/hip_runtime.h>
#include <math.h>

#define NEG_SLOPE 0.2f

// ---------------------------------------------------------------------------
// K0: out[n,d] = mean_h bias[h*32+d]  (aggregation adds on top); denom = 0
// ---------------------------------------------------------------------------
__global__ void k_init(float* __restrict__ out, float* __restrict__ denom,
                       const float* __restrict__ bias, int N) {
    int idx = blockIdx.x * blockDim.x + threadIdx.x;
    int total = N * 32;
    if (idx < total) {
        int d = idx & 31;
        out[idx] = 0.25f * (bias[d] + bias[32 + d] + bias[64 + d] + bias[96 + d]);
    } else if (idx < total + N * 4) {
        denom[idx - total] = 0.0f;
    }
}

// ---------------------------------------------------------------------------
// K1: feat = h @ W.T   (fp32, VALU).  Block tile 64 rows x 128 cols,
// thread tile 8 rows x 4 cols (cols strided by 32 for LDS bank spread).
// A staged row-major [64][68] (pad 4 -> 2-way broadcast reads, free).
// B staged [128][64] with 16B-slot XOR swizzle -> reads hit the 4-cyc floor.
// All LDS reads are b128.  ~VALU-bound.
// ---------------------------------------------------------------------------
__global__ __launch_bounds__(256, 3) void k_gemm(const float* __restrict__ h,
                                                 const float* __restrict__ W,
                                                 float* __restrict__ feat, int N) {
    __shared__ float As[64 * 68];
    __shared__ float Bs[128 * 64];
    const int tid = threadIdx.x;
    const int rb = blockIdx.x * 64;
    const int tc = tid & 31;   // col group: cols tc + 32*j
    const int tr = tid >> 5;   // row group: rows tr*8 + i

    float acc[8][4];
#pragma unroll
    for (int i = 0; i < 8; ++i)
#pragma unroll
        for (int j = 0; j < 4; ++j) acc[i][j] = 0.0f;

    for (int kch = 0; kch < 2; ++kch) {
        if (kch) __syncthreads();
        // stage A: 64 rows x 64 k, coalesced float4, conflict-free writes
#pragma unroll
        for (int i = 0; i < 4; ++i) {
            int chunk = i * 256 + tid;
            int r = chunk >> 4;
            int kc = (chunk & 15) << 2;
            int row = rb + r;
            float4 v = make_float4(0.f, 0.f, 0.f, 0.f);
            if (row < N) v = *(const float4*)(h + (size_t)row * 128 + kch * 64 + kc);
            *(float4*)(As + r * 68 + kc) = v;
        }
        // stage B: 128 cols x 64 k, slot-swizzled
#pragma unroll
        for (int i = 0; i < 8; ++i) {
            int chunk = i * 256 + tid;
            int c = chunk >> 4;
            int kc = (chunk & 15) << 2;
            float4 v = *(const float4*)(W + (size_t)c * 128 + kch * 64 + kc);
            int slot = (kc >> 2) ^ (c & 7);
            *(float4*)(Bs + (c << 6) + (slot << 2)) = v;
        }
        __syncthreads();

#pragma unroll 4
        for (int k4 = 0; k4 < 64; k4 += 4) {
            float4 b[4];
#pragma unroll
            for (int j = 0; j < 4; ++j) {
                int c = tc + 32 * j;
                int slot = (k4 >> 2) ^ (c & 7);
                b[j] = *(const float4*)(Bs + (c << 6) + (slot << 2));
            }
            float4 a[8];
#pragma unroll
            for (int i = 0; i < 8; ++i)
                a[i] = *(const float4*)(As + (tr * 8 + i) * 68 + k4);
#pragma unroll
            for (int i = 0; i < 8; ++i)
#pragma unroll
                for (int j = 0; j < 4; ++j)
                    acc[i][j] += a[i].x * b[j].x + a[i].y * b[j].y +
                                 a[i].z * b[j].z + a[i].w * b[j].w;
        }
    }
#pragma unroll
    for (int i = 0; i < 8; ++i) {
        int row = rb + tr * 8 + i;
        if (row < N) {
#pragma unroll
            for (int j = 0; j < 4; ++j)
                feat[(size_t)row * 128 + tc + 32 * j] = acc[i][j];
        }
    }
}

// ---------------------------------------------------------------------------
// K2: el[n,h] = <feat[n,h,:], attn_l[h]>, er likewise.  Thread per (n,h).
// ---------------------------------------------------------------------------
__global__ void k_elr(const float* __restrict__ feat, const float* __restrict__ attn_l,
                      const float* __restrict__ attn_r, float* __restrict__ el,
                      float* __restrict__ er, int N) {
    int idx = blockIdx.x * blockDim.x + threadIdx.x;
    if (idx >= N * 4) return;
    int n = idx >> 2, hh = idx & 3;
    const float4* f4 = (const float4*)(feat + (size_t)n * 128 + hh * 32);
    const float4* l4 = (const float4*)(attn_l + hh * 32);
    const float4* r4 = (const float4*)(attn_r + hh * 32);
    float a = 0.f, b = 0.f;
#pragma unroll
    for (int t = 0; t < 8; ++t) {
        float4 f = f4[t], la = l4[t], ra = r4[t];
        a += f.x * la.x + f.y * la.y + f.z * la.z + f.w * la.w;
        b += f.x * ra.x + f.y * ra.y + f.z * ra.z + f.w * ra.w;
    }
    el[idx] = a;
    er[idx] = b;
}

// ---------------------------------------------------------------------------
// K3: per edge: a_h = exp(lrelu(el[src]+er[dst])); denom[dst,h] += a_h
// (max-subtraction skipped: alpha is invariant to it and logits are bounded)
// ---------------------------------------------------------------------------
__global__ void k_edge_denom(const int* __restrict__ src, const int* __restrict__ dst,
                             const float* __restrict__ el, const float* __restrict__ er,
                             float* __restrict__ denom, int E) {
    int e = blockIdx.x * blockDim.x + threadIdx.x;
    if (e >= E) return;
    int s = src[e], d = dst[e];
    float4 l = *(const float4*)(el + 4 * (size_t)s);
    float4 r = *(const float4*)(er + 4 * (size_t)d);
    float v0 = l.x + r.x; v0 = v0 > 0.f ? v0 : NEG_SLOPE * v0;
    float v1 = l.y + r.y; v1 = v1 > 0.f ? v1 : NEG_SLOPE * v1;
    float v2 = l.z + r.z; v2 = v2 > 0.f ? v2 : NEG_SLOPE * v2;
    float v3 = l.w + r.w; v3 = v3 > 0.f ? v3 : NEG_SLOPE * v3;
    float* dn = denom + 4 * (size_t)d;
    atomicAdd(dn + 0, __expf(v0));
    atomicAdd(dn + 1, __expf(v1));
    atomicAdd(dn + 2, __expf(v2));
    atomicAdd(dn + 3, __expf(v3));
}

// ---------------------------------------------------------------------------
// K4: 32 lanes per edge (lane = output dim d).  Heads folded per edge:
// msg[d] = sum_h alpha_h * feat[src,h,d];  out[dst,d] += 0.25*msg[d].
// feat gathers are 4x 128B coalesced segments per edge group.
// ---------------------------------------------------------------------------
__global__ void k_edge_agg(const int* __restrict__ src, const int* __restrict__ dst,
                           const float* __restrict__ el, const float* __restrict__ er,
                           const float* __restrict__ denom, const float* __restrict__ feat,
                           float* __restrict__ out, int E) {
    long total = (long)E * 32;
    long stride = (long)gridDim.x * blockDim.x;
    for (long u = blockIdx.x * (long)blockDim.x + threadIdx.x; u < total; u += stride) {
        int e = (int)(u >> 5);
        int d = (int)(u & 31);
        int s = src[e], dd = dst[e];
        float4 l = *(const float4*)(el + 4 * (size_t)s);
        float4 r = *(const float4*)(er + 4 * (size_t)dd);
        float4 dn = *(const float4*)(denom + 4 * (size_t)dd);
        float v0 = l.x + r.x; v0 = v0 > 0.f ? v0 : NEG_SLOPE * v0;
        float v1 = l.y + r.y; v1 = v1 > 0.f ? v1 : NEG_SLOPE * v1;
        float v2 = l.z + r.z; v2 = v2 > 0.f ? v2 : NEG_SLOPE * v2;
        float v3 = l.w + r.w; v3 = v3 > 0.f ? v3 : NEG_SLOPE * v3;
        float a0 = __expf(v0) / dn.x;
        float a1 = __expf(v1) / dn.y;
        float a2 = __expf(v2) / dn.z;
        float a3 = __expf(v3) / dn.w;
        const float* fp = feat + (size_t)s * 128 + d;
        float m = a0 * fp[0] + a1 * fp[32] + a2 * fp[64] + a3 * fp[96];
        atomicAdd(out + (size_t)dd * 32 + d, 0.25f * m);
    }
}

// ---------------------------------------------------------------------------
extern "C" void kernel_launch(void* const* d_in, const int* in_sizes, int n_in,
                              void* d_out, int out_size, void* d_ws, size_t ws_size,
                              hipStream_t stream) {
    const float* h      = (const float*)d_in[0];
    const int*   src    = (const int*)d_in[1];
    const int*   dst    = (const int*)d_in[2];
    // d_in[3] rel_types: unused by the reference output
    const float* W      = (const float*)d_in[4];
    const float* attn_l = (const float*)d_in[5];
    const float* attn_r = (const float*)d_in[6];
    const float* bias   = (const float*)d_in[7];
    // d_in[8] rel_emb: unused by the reference output
    float* out = (float*)d_out;

    const int N = in_sizes[0] / 128;
    const int E = in_sizes[1];

    // workspace layout (fp32): feat [N,128] | el [N,4] | er [N,4] | denom [N,4]
    float* feat  = (float*)d_ws;
    float* el    = feat + (size_t)N * 128;
    float* er    = el + (size_t)N * 4;
    float* denom = er + (size_t)N * 4;

    // K0: init out (bias mean) + zero denom
    {
        int total = N * 36;
        k_init<<<(total + 255) / 256, 256, 0, stream>>>(out, denom, bias, N);
    }
    // K1: GEMM
    k_gemm<<<(N + 63) / 64, 256, 0, stream>>>(h, W, feat, N);
    // K2: el / er
    k_elr<<<(N * 4 + 255) / 256, 256, 0, stream>>>(feat, attn_l, attn_r, el, er, N);
    // K3: denominators
    k_edge_denom<<<(E + 255) / 256, 256, 0, stream>>>(src, dst, el, er, denom, E);
    // K4: aggregate (grid-stride, 32 lanes per edge)
    k_edge_agg<<<8192, 256, 0, stream>>>(src, dst, el, er, denom, feat, out, E);
}

// Round 3
// 435.335 us; speedup vs baseline: 1.6111x; 1.6111x over previous
//
#include <hip/hip_runtime.h>
#include <math.h>

#define NEG_SLOPE 0.2f

// ===========================================================================
// Shared front-end kernels
// ===========================================================================

// K1: feat = h @ W.T   (fp32, VALU).  64x128 block tile, 8x4 thread tile.
__global__ __launch_bounds__(256, 3) void k_gemm(const float* __restrict__ h,
                                                 const float* __restrict__ W,
                                                 float* __restrict__ feat, int N) {
    __shared__ float As[64 * 68];
    __shared__ float Bs[128 * 64];
    const int tid = threadIdx.x;
    const int rb = blockIdx.x * 64;
    const int tc = tid & 31;
    const int tr = tid >> 5;

    float acc[8][4];
#pragma unroll
    for (int i = 0; i < 8; ++i)
#pragma unroll
        for (int j = 0; j < 4; ++j) acc[i][j] = 0.0f;

    for (int kch = 0; kch < 2; ++kch) {
        if (kch) __syncthreads();
#pragma unroll
        for (int i = 0; i < 4; ++i) {
            int chunk = i * 256 + tid;
            int r = chunk >> 4;
            int kc = (chunk & 15) << 2;
            int row = rb + r;
            float4 v = make_float4(0.f, 0.f, 0.f, 0.f);
            if (row < N) v = *(const float4*)(h + (size_t)row * 128 + kch * 64 + kc);
            *(float4*)(As + r * 68 + kc) = v;
        }
#pragma unroll
        for (int i = 0; i < 8; ++i) {
            int chunk = i * 256 + tid;
            int c = chunk >> 4;
            int kc = (chunk & 15) << 2;
            float4 v = *(const float4*)(W + (size_t)c * 128 + kch * 64 + kc);
            int slot = (kc >> 2) ^ (c & 7);
            *(float4*)(Bs + (c << 6) + (slot << 2)) = v;
        }
        __syncthreads();

#pragma unroll 4
        for (int k4 = 0; k4 < 64; k4 += 4) {
            float4 b[4];
#pragma unroll
            for (int j = 0; j < 4; ++j) {
                int c = tc + 32 * j;
                int slot = (k4 >> 2) ^ (c & 7);
                b[j] = *(const float4*)(Bs + (c << 6) + (slot << 2));
            }
            float4 a[8];
#pragma unroll
            for (int i = 0; i < 8; ++i)
                a[i] = *(const float4*)(As + (tr * 8 + i) * 68 + k4);
#pragma unroll
            for (int i = 0; i < 8; ++i)
#pragma unroll
                for (int j = 0; j < 4; ++j)
                    acc[i][j] += a[i].x * b[j].x + a[i].y * b[j].y +
                                 a[i].z * b[j].z + a[i].w * b[j].w;
        }
    }
#pragma unroll
    for (int i = 0; i < 8; ++i) {
        int row = rb + tr * 8 + i;
        if (row < N) {
#pragma unroll
            for (int j = 0; j < 4; ++j)
                feat[(size_t)row * 128 + tc + 32 * j] = acc[i][j];
        }
    }
}

// K2: el[n,h] = <feat[n,h,:], attn_l[h]>, er likewise.
__global__ void k_elr(const float* __restrict__ feat, const float* __restrict__ attn_l,
                      const float* __restrict__ attn_r, float* __restrict__ el,
                      float* __restrict__ er, int N) {
    int idx = blockIdx.x * blockDim.x + threadIdx.x;
    if (idx >= N * 4) return;
    int n = idx >> 2, hh = idx & 3;
    const float4* f4 = (const float4*)(feat + (size_t)n * 128 + hh * 32);
    const float4* l4 = (const float4*)(attn_l + hh * 32);
    const float4* r4 = (const float4*)(attn_r + hh * 32);
    float a = 0.f, b = 0.f;
#pragma unroll
    for (int t = 0; t < 8; ++t) {
        float4 f = f4[t], la = l4[t], ra = r4[t];
        a += f.x * la.x + f.y * la.y + f.z * la.z + f.w * la.w;
        b += f.x * ra.x + f.y * ra.y + f.z * ra.z + f.w * ra.w;
    }
    el[idx] = a;
    er[idx] = b;
}

// ===========================================================================
// CSR path: 1 atomic per edge, then pull-mode fused softmax+aggregate
// ===========================================================================

// pos[e] = rank of edge e within its destination segment; cnt[n] ends as deg(n)
__global__ void k_hist(const int* __restrict__ dst, int* __restrict__ cnt,
                       int* __restrict__ pos, int E) {
    int e = blockIdx.x * blockDim.x + threadIdx.x;
    if (e < E) pos[e] = atomicAdd(&cnt[dst[e]], 1);
}

// S1: per-block sums of cnt
__global__ void k_scan1(const int* __restrict__ cnt, int* __restrict__ bsum, int N) {
    __shared__ int sd[256];
    int t = threadIdx.x;
    int i = blockIdx.x * 256 + t;
    sd[t] = (i < N) ? cnt[i] : 0;
    __syncthreads();
    for (int s = 128; s > 0; s >>= 1) {
        if (t < s) sd[t] += sd[t + s];
        __syncthreads();
    }
    if (t == 0) bsum[blockIdx.x] = sd[0];
}

// S2: exclusive scan of block sums (single block, nb <= 1024)
__global__ void k_scan2(int* __restrict__ bsum, int nb) {
    __shared__ int sd[1024];
    int t = threadIdx.x;
    sd[t] = (t < nb) ? bsum[t] : 0;
    __syncthreads();
    for (int off = 1; off < 1024; off <<= 1) {
        int add = (t >= off) ? sd[t - off] : 0;
        __syncthreads();
        sd[t] += add;
        __syncthreads();
    }
    if (t < nb) bsum[t] = (t == 0) ? 0 : sd[t - 1];
}

// S3: row[i] = bsum[block] + exclusive_scan_within_block(cnt)
__global__ void k_scan3(const int* __restrict__ cnt, const int* __restrict__ bsum,
                        int* __restrict__ row, int N) {
    __shared__ int sd[256];
    int t = threadIdx.x;
    int i = blockIdx.x * 256 + t;
    int v = (i < N) ? cnt[i] : 0;
    sd[t] = v;
    __syncthreads();
    for (int off = 1; off < 256; off <<= 1) {
        int add = (t >= off) ? sd[t - off] : 0;
        __syncthreads();
        sd[t] += add;
        __syncthreads();
    }
    if (i < N) row[i] = bsum[blockIdx.x] + sd[t] - v;
}

// Scatter: esrc[row[dst]+pos] = src   (plain L2-cached stores, no atomics)
__global__ void k_scatter(const int* __restrict__ src, const int* __restrict__ dst,
                          const int* __restrict__ pos, const int* __restrict__ row,
                          int* __restrict__ esrc, int E) {
    int e = blockIdx.x * blockDim.x + threadIdx.x;
    if (e < E) esrc[row[dst[e]] + pos[e]] = src[e];
}

// Pull: one 64-lane wave per dst node; lanes 0-31 / 32-63 take alternating
// edges; lane d accumulates msg_h[d] and denom_h in registers. No atomics.
__global__ __launch_bounds__(256) void k_pull(const int* __restrict__ esrc,
                                              const int* __restrict__ row,
                                              const int* __restrict__ cnt,
                                              const float* __restrict__ el,
                                              const float* __restrict__ er,
                                              const float* __restrict__ feat,
                                              const float* __restrict__ bias,
                                              float* __restrict__ out, int N) {
    int wave = (int)((blockIdx.x * (size_t)blockDim.x + threadIdx.x) >> 6);
    if (wave >= N) return;
    int lane = threadIdx.x & 63;
    int half = lane >> 5;
    int d = lane & 31;
    int start = row[wave];
    int deg = cnt[wave];
    float4 r4 = *(const float4*)(er + 4 * (size_t)wave);

    float acc0 = 0.f, acc1 = 0.f, acc2 = 0.f, acc3 = 0.f;
    float dn0 = 0.f, dn1 = 0.f, dn2 = 0.f, dn3 = 0.f;

    int s = (half < deg) ? esrc[start + half] : 0;
    for (int i = half; i < deg; i += 2) {
        int s_next = (i + 2 < deg) ? esrc[start + i + 2] : 0;
        float4 l4 = *(const float4*)(el + 4 * (size_t)s);
        const float* fp = feat + (size_t)s * 128 + d;
        float f0 = fp[0], f1 = fp[32], f2 = fp[64], f3 = fp[96];
        float v0 = l4.x + r4.x; v0 = v0 > 0.f ? v0 : NEG_SLOPE * v0;
        float v1 = l4.y + r4.y; v1 = v1 > 0.f ? v1 : NEG_SLOPE * v1;
        float v2 = l4.z + r4.z; v2 = v2 > 0.f ? v2 : NEG_SLOPE * v2;
        float v3 = l4.w + r4.w; v3 = v3 > 0.f ? v3 : NEG_SLOPE * v3;
        float a0 = __expf(v0), a1 = __expf(v1), a2 = __expf(v2), a3 = __expf(v3);
        dn0 += a0; dn1 += a1; dn2 += a2; dn3 += a3;
        acc0 += a0 * f0; acc1 += a1 * f1; acc2 += a2 * f2; acc3 += a3 * f3;
        s = s_next;
    }
    // combine the two edge-halves (lane d and lane d+32 hold partials for dim d)
    acc0 += __shfl_xor(acc0, 32); acc1 += __shfl_xor(acc1, 32);
    acc2 += __shfl_xor(acc2, 32); acc3 += __shfl_xor(acc3, 32);
    dn0 += __shfl_xor(dn0, 32);   dn1 += __shfl_xor(dn1, 32);
    dn2 += __shfl_xor(dn2, 32);   dn3 += __shfl_xor(dn3, 32);

    if (half == 0) {
        float m = 0.f;
        if (dn0 > 0.f)
            m = acc0 / dn0 + acc1 / dn1 + acc2 / dn2 + acc3 / dn3;
        float b = 0.25f * (bias[d] + bias[32 + d] + bias[64 + d] + bias[96 + d]);
        out[(size_t)wave * 32 + d] = 0.25f * m + b;
    }
}

// ===========================================================================
// Legacy atomic path (fallback if ws too small for CSR buffers)
// ===========================================================================
__global__ void k_init(float* __restrict__ out, float* __restrict__ denom,
                       const float* __restrict__ bias, int N) {
    int idx = blockIdx.x * blockDim.x + threadIdx.x;
    int total = N * 32;
    if (idx < total) {
        int d = idx & 31;
        out[idx] = 0.25f * (bias[d] + bias[32 + d] + bias[64 + d] + bias[96 + d]);
    } else if (idx < total + N * 4) {
        denom[idx - total] = 0.0f;
    }
}

__global__ void k_edge_denom(const int* __restrict__ src, const int* __restrict__ dst,
                             const float* __restrict__ el, const float* __restrict__ er,
                             float* __restrict__ denom, int E) {
    int e = blockIdx.x * blockDim.x + threadIdx.x;
    if (e >= E) return;
    int s = src[e], d = dst[e];
    float4 l = *(const float4*)(el + 4 * (size_t)s);
    float4 r = *(const float4*)(er + 4 * (size_t)d);
    float v0 = l.x + r.x; v0 = v0 > 0.f ? v0 : NEG_SLOPE * v0;
    float v1 = l.y + r.y; v1 = v1 > 0.f ? v1 : NEG_SLOPE * v1;
    float v2 = l.z + r.z; v2 = v2 > 0.f ? v2 : NEG_SLOPE * v2;
    float v3 = l.w + r.w; v3 = v3 > 0.f ? v3 : NEG_SLOPE * v3;
    float* dn = denom + 4 * (size_t)d;
    atomicAdd(dn + 0, __expf(v0));
    atomicAdd(dn + 1, __expf(v1));
    atomicAdd(dn + 2, __expf(v2));
    atomicAdd(dn + 3, __expf(v3));
}

__global__ void k_edge_agg(const int* __restrict__ src, const int* __restrict__ dst,
                           const float* __restrict__ el, const float* __restrict__ er,
                           const float* __restrict__ denom, const float* __restrict__ feat,
                           float* __restrict__ out, int E) {
    long total = (long)E * 32;
    long stride = (long)gridDim.x * blockDim.x;
    for (long u = blockIdx.x * (long)blockDim.x + threadIdx.x; u < total; u += stride) {
        int e = (int)(u >> 5);
        int d = (int)(u & 31);
        int s = src[e], dd = dst[e];
        float4 l = *(const float4*)(el + 4 * (size_t)s);
        float4 r = *(const float4*)(er + 4 * (size_t)dd);
        float4 dn = *(const float4*)(denom + 4 * (size_t)dd);
        float v0 = l.x + r.x; v0 = v0 > 0.f ? v0 : NEG_SLOPE * v0;
        float v1 = l.y + r.y; v1 = v1 > 0.f ? v1 : NEG_SLOPE * v1;
        float v2 = l.z + r.z; v2 = v2 > 0.f ? v2 : NEG_SLOPE * v2;
        float v3 = l.w + r.w; v3 = v3 > 0.f ? v3 : NEG_SLOPE * v3;
        float a0 = __expf(v0) / dn.x;
        float a1 = __expf(v1) / dn.y;
        float a2 = __expf(v2) / dn.z;
        float a3 = __expf(v3) / dn.w;
        const float* fp = feat + (size_t)s * 128 + d;
        float m = a0 * fp[0] + a1 * fp[32] + a2 * fp[64] + a3 * fp[96];
        atomicAdd(out + (size_t)dd * 32 + d, 0.25f * m);
    }
}

// ===========================================================================
extern "C" void kernel_launch(void* const* d_in, const int* in_sizes, int n_in,
                              void* d_out, int out_size, void* d_ws, size_t ws_size,
                              hipStream_t stream) {
    const float* h      = (const float*)d_in[0];
    const int*   src    = (const int*)d_in[1];
    const int*   dst    = (const int*)d_in[2];
    const float* W      = (const float*)d_in[4];
    const float* attn_l = (const float*)d_in[5];
    const float* attn_r = (const float*)d_in[6];
    const float* bias   = (const float*)d_in[7];
    float* out = (float*)d_out;

    const int N = in_sizes[0] / 128;
    const int E = in_sizes[1];

    // Common: feat [N,128] | el [N,4] | er [N,4]
    float* feat = (float*)d_ws;
    float* el   = feat + (size_t)N * 128;
    float* er   = el + (size_t)N * 4;

    size_t csr_need = (size_t)(N * 136 + 2 * N + 1024 + 2 * E) * 4;

    k_gemm<<<(N + 63) / 64, 256, 0, stream>>>(h, W, feat, N);
    k_elr<<<(N * 4 + 255) / 256, 256, 0, stream>>>(feat, attn_l, attn_r, el, er, N);

    if (ws_size >= csr_need) {
        // CSR path
        int* cnt  = (int*)(er + (size_t)N * 4);
        int* row  = cnt + N;
        int* bsum = row + N;
        int* pos  = bsum + 1024;
        int* esrc = pos + E;
        int nb = (N + 255) / 256;  // <= 1024 for N <= 262144

        hipMemsetAsync(cnt, 0, (size_t)N * 4, stream);
        k_hist<<<(E + 255) / 256, 256, 0, stream>>>(dst, cnt, pos, E);
        k_scan1<<<nb, 256, 0, stream>>>(cnt, bsum, N);
        k_scan2<<<1, 1024, 0, stream>>>(bsum, nb);
        k_scan3<<<nb, 256, 0, stream>>>(cnt, bsum, row, N);
        k_scatter<<<(E + 255) / 256, 256, 0, stream>>>(src, dst, pos, row, esrc, E);
        k_pull<<<(N * 64 + 255) / 256, 256, 0, stream>>>(esrc, row, cnt, el, er, feat,
                                                         bias, out, N);
    } else {
        // Legacy atomic path
        float* denom = er + (size_t)N * 4;
        k_init<<<(N * 36 + 255) / 256, 256, 0, stream>>>(out, denom, bias, N);
        k_edge_denom<<<(E + 255) / 256, 256, 0, stream>>>(src, dst, el, er, denom, E);
        k_edge_agg<<<8192, 256, 0, stream>>>(src, dst, el, er, denom, feat, out, E);
    }
}

// Round 4
// 407.397 us; speedup vs baseline: 1.7215x; 1.0686x over previous
//
#include <hip/hip_runtime.h>
#include <hip/hip_bf16.h>
#include <math.h>

#define NEG_SLOPE 0.2f

__device__ __forceinline__ float bf2f(unsigned int hw) {
    return __uint_as_float(hw << 16);
}
__device__ __forceinline__ unsigned short f2bf(float f) {
    unsigned int u = __float_as_uint(f);
    u += 0x7FFFu + ((u >> 16) & 1u);   // round-to-nearest-even
    return (unsigned short)(u >> 16);
}

// ===========================================================================
// K1: feat = h @ W.T (fp32 VALU GEMM), epilogue packs bf16 into
// featp[n][d][h] (dim-major, 4 heads adjacent -> one 8B load per edge-lane).
// 64x128 block tile, 8 rows x 4 cols per thread; col c = tc + 32*j => head j,
// dim tc, so acc[i][0..3] is exactly the packed ushort4 for (row i, dim tc).
// ===========================================================================
__global__ __launch_bounds__(256, 3) void k_gemm(const float* __restrict__ h,
                                                 const float* __restrict__ W,
                                                 unsigned short* __restrict__ featp,
                                                 int N) {
    __shared__ float As[64 * 68];
    __shared__ float Bs[128 * 64];
    const int tid = threadIdx.x;
    const int rb = blockIdx.x * 64;
    const int tc = tid & 31;
    const int tr = tid >> 5;

    float acc[8][4];
#pragma unroll
    for (int i = 0; i < 8; ++i)
#pragma unroll
        for (int j = 0; j < 4; ++j) acc[i][j] = 0.0f;

    for (int kch = 0; kch < 2; ++kch) {
        if (kch) __syncthreads();
#pragma unroll
        for (int i = 0; i < 4; ++i) {
            int chunk = i * 256 + tid;
            int r = chunk >> 4;
            int kc = (chunk & 15) << 2;
            int row = rb + r;
            float4 v = make_float4(0.f, 0.f, 0.f, 0.f);
            if (row < N) v = *(const float4*)(h + (size_t)row * 128 + kch * 64 + kc);
            *(float4*)(As + r * 68 + kc) = v;
        }
#pragma unroll
        for (int i = 0; i < 8; ++i) {
            int chunk = i * 256 + tid;
            int c = chunk >> 4;
            int kc = (chunk & 15) << 2;
            float4 v = *(const float4*)(W + (size_t)c * 128 + kch * 64 + kc);
            int slot = (kc >> 2) ^ (c & 7);
            *(float4*)(Bs + (c << 6) + (slot << 2)) = v;
        }
        __syncthreads();

#pragma unroll 4
        for (int k4 = 0; k4 < 64; k4 += 4) {
            float4 b[4];
#pragma unroll
            for (int j = 0; j < 4; ++j) {
                int c = tc + 32 * j;
                int slot = (k4 >> 2) ^ (c & 7);
                b[j] = *(const float4*)(Bs + (c << 6) + (slot << 2));
            }
            float4 a[8];
#pragma unroll
            for (int i = 0; i < 8; ++i)
                a[i] = *(const float4*)(As + (tr * 8 + i) * 68 + k4);
#pragma unroll
            for (int i = 0; i < 8; ++i)
#pragma unroll
                for (int j = 0; j < 4; ++j)
                    acc[i][j] += a[i].x * b[j].x + a[i].y * b[j].y +
                                 a[i].z * b[j].z + a[i].w * b[j].w;
        }
    }
#pragma unroll
    for (int i = 0; i < 8; ++i) {
        int row = rb + tr * 8 + i;
        if (row < N) {
            ushort4 pk;
            pk.x = f2bf(acc[i][0]);
            pk.y = f2bf(acc[i][1]);
            pk.z = f2bf(acc[i][2]);
            pk.w = f2bf(acc[i][3]);
            *(ushort4*)(featp + (size_t)row * 128 + tc * 4) = pk;
        }
    }
}

// ===========================================================================
// K2: el[n,h] = sum_d featp[n,d,h]*attn_l[h,d]; er likewise.
// 32 lanes per node (lane=d), 8B packed load, shfl_xor reduce within 32-group.
// ===========================================================================
__global__ void k_elr(const unsigned short* __restrict__ featp,
                      const float* __restrict__ attn_l,
                      const float* __restrict__ attn_r,
                      float* __restrict__ el, float* __restrict__ er, int N) {
    int g = blockIdx.x * blockDim.x + threadIdx.x;
    int node = g >> 5;
    int d = g & 31;
    if (node >= N) return;
    uint2 u = *(const uint2*)(featp + (size_t)node * 128 + d * 4);
    float f0 = bf2f(u.x & 0xffffu);
    float f1 = bf2f(u.x >> 16);
    float f2 = bf2f(u.y & 0xffffu);
    float f3 = bf2f(u.y >> 16);
    float pl0 = f0 * attn_l[d],      pr0 = f0 * attn_r[d];
    float pl1 = f1 * attn_l[32 + d], pr1 = f1 * attn_r[32 + d];
    float pl2 = f2 * attn_l[64 + d], pr2 = f2 * attn_r[64 + d];
    float pl3 = f3 * attn_l[96 + d], pr3 = f3 * attn_r[96 + d];
#pragma unroll
    for (int m = 1; m < 32; m <<= 1) {
        pl0 += __shfl_xor(pl0, m); pr0 += __shfl_xor(pr0, m);
        pl1 += __shfl_xor(pl1, m); pr1 += __shfl_xor(pr1, m);
        pl2 += __shfl_xor(pl2, m); pr2 += __shfl_xor(pr2, m);
        pl3 += __shfl_xor(pl3, m); pr3 += __shfl_xor(pr3, m);
    }
    if (d == 0) {
        *(float4*)(el + (size_t)node * 4) = make_float4(pl0, pl1, pl2, pl3);
        *(float4*)(er + (size_t)node * 4) = make_float4(pr0, pr1, pr2, pr3);
    }
}

// ===========================================================================
// CSR build: 1 int atomic per edge + scans + scatter
// ===========================================================================
__global__ void k_hist(const int* __restrict__ dst, int* __restrict__ cnt,
                       int* __restrict__ pos, int E) {
    int e = blockIdx.x * blockDim.x + threadIdx.x;
    if (e < E) pos[e] = atomicAdd(&cnt[dst[e]], 1);
}

__global__ void k_scan1(const int* __restrict__ cnt, int* __restrict__ bsum, int N) {
    __shared__ int sd[256];
    int t = threadIdx.x;
    int i = blockIdx.x * 256 + t;
    sd[t] = (i < N) ? cnt[i] : 0;
    __syncthreads();
    for (int s = 128; s > 0; s >>= 1) {
        if (t < s) sd[t] += sd[t + s];
        __syncthreads();
    }
    if (t == 0) bsum[blockIdx.x] = sd[0];
}

__global__ void k_scan2(int* __restrict__ bsum, int nb) {
    __shared__ int sd[1024];
    int t = threadIdx.x;
    sd[t] = (t < nb) ? bsum[t] : 0;
    __syncthreads();
    for (int off = 1; off < 1024; off <<= 1) {
        int add = (t >= off) ? sd[t - off] : 0;
        __syncthreads();
        sd[t] += add;
        __syncthreads();
    }
    if (t < nb) bsum[t] = (t == 0) ? 0 : sd[t - 1];
}

__global__ void k_scan3(const int* __restrict__ cnt, const int* __restrict__ bsum,
                        int* __restrict__ row, int N) {
    __shared__ int sd[256];
    int t = threadIdx.x;
    int i = blockIdx.x * 256 + t;
    int v = (i < N) ? cnt[i] : 0;
    sd[t] = v;
    __syncthreads();
    for (int off = 1; off < 256; off <<= 1) {
        int add = (t >= off) ? sd[t - off] : 0;
        __syncthreads();
        sd[t] += add;
        __syncthreads();
    }
    if (i < N) row[i] = bsum[blockIdx.x] + sd[t] - v;
}

__global__ void k_scatter(const int* __restrict__ src, const int* __restrict__ dst,
                          const int* __restrict__ pos, const int* __restrict__ row,
                          int* __restrict__ esrc, int E) {
    int e = blockIdx.x * blockDim.x + threadIdx.x;
    if (e < E) esrc[row[dst[e]] + pos[e]] = src[e];
}

// ===========================================================================
// Pull: one 64-lane wave per dst node; halves take alternating edges; lane d
// does ONE 8B packed-bf16 load per edge covering all 4 heads. No atomics.
// ===========================================================================
__global__ __launch_bounds__(256) void k_pull(const int* __restrict__ esrc,
                                              const int* __restrict__ row,
                                              const int* __restrict__ cnt,
                                              const float* __restrict__ el,
                                              const float* __restrict__ er,
                                              const unsigned short* __restrict__ featp,
                                              const float* __restrict__ bias,
                                              float* __restrict__ out, int N) {
    int wave = (int)((blockIdx.x * (size_t)blockDim.x + threadIdx.x) >> 6);
    if (wave >= N) return;
    int lane = threadIdx.x & 63;
    int half = lane >> 5;
    int d = lane & 31;
    int start = row[wave];
    int deg = cnt[wave];
    float4 r4 = *(const float4*)(er + 4 * (size_t)wave);

    float acc0 = 0.f, acc1 = 0.f, acc2 = 0.f, acc3 = 0.f;
    float dn0 = 0.f, dn1 = 0.f, dn2 = 0.f, dn3 = 0.f;

    int s = (half < deg) ? esrc[start + half] : 0;
    for (int i = half; i < deg; i += 2) {
        int s_next = (i + 2 < deg) ? esrc[start + i + 2] : 0;
        float4 l4 = *(const float4*)(el + 4 * (size_t)s);
        uint2 u = *(const uint2*)(featp + (size_t)s * 128 + d * 4);
        float f0 = bf2f(u.x & 0xffffu);
        float f1 = bf2f(u.x >> 16);
        float f2 = bf2f(u.y & 0xffffu);
        float f3 = bf2f(u.y >> 16);
        float v0 = l4.x + r4.x; v0 = v0 > 0.f ? v0 : NEG_SLOPE * v0;
        float v1 = l4.y + r4.y; v1 = v1 > 0.f ? v1 : NEG_SLOPE * v1;
        float v2 = l4.z + r4.z; v2 = v2 > 0.f ? v2 : NEG_SLOPE * v2;
        float v3 = l4.w + r4.w; v3 = v3 > 0.f ? v3 : NEG_SLOPE * v3;
        float a0 = __expf(v0), a1 = __expf(v1), a2 = __expf(v2), a3 = __expf(v3);
        dn0 += a0; dn1 += a1; dn2 += a2; dn3 += a3;
        acc0 += a0 * f0; acc1 += a1 * f1; acc2 += a2 * f2; acc3 += a3 * f3;
        s = s_next;
    }
    acc0 += __shfl_xor(acc0, 32); acc1 += __shfl_xor(acc1, 32);
    acc2 += __shfl_xor(acc2, 32); acc3 += __shfl_xor(acc3, 32);
    dn0 += __shfl_xor(dn0, 32);   dn1 += __shfl_xor(dn1, 32);
    dn2 += __shfl_xor(dn2, 32);   dn3 += __shfl_xor(dn3, 32);

    if (half == 0) {
        float m = 0.f;
        if (dn0 > 0.f)
            m = acc0 / dn0 + acc1 / dn1 + acc2 / dn2 + acc3 / dn3;
        float b = 0.25f * (bias[d] + bias[32 + d] + bias[64 + d] + bias[96 + d]);
        out[(size_t)wave * 32 + d] = 0.25f * m + b;
    }
}

// ===========================================================================
extern "C" void kernel_launch(void* const* d_in, const int* in_sizes, int n_in,
                              void* d_out, int out_size, void* d_ws, size_t ws_size,
                              hipStream_t stream) {
    const float* h      = (const float*)d_in[0];
    const int*   src    = (const int*)d_in[1];
    const int*   dst    = (const int*)d_in[2];
    const float* W      = (const float*)d_in[4];
    const float* attn_l = (const float*)d_in[5];
    const float* attn_r = (const float*)d_in[6];
    const float* bias   = (const float*)d_in[7];
    float* out = (float*)d_out;

    const int N = in_sizes[0] / 128;
    const int E = in_sizes[1];

    // ws layout: el [N,4] f32 | er [N,4] f32 | featp [N,128] bf16 |
    //            cnt [N] | row [N] | bsum [1024] | pos [E] | esrc [E]
    float* el = (float*)d_ws;
    float* er = el + (size_t)N * 4;
    unsigned short* featp = (unsigned short*)(er + (size_t)N * 4);
    int* cnt  = (int*)(featp + (size_t)N * 128);
    int* row  = cnt + N;
    int* bsum = row + N;
    int* pos  = bsum + 1024;
    int* esrc = pos + E;
    int nb = (N + 255) / 256;  // <= 1024 for N <= 262144

    k_gemm<<<(N + 63) / 64, 256, 0, stream>>>(h, W, featp, N);
    k_elr<<<((size_t)N * 32 + 255) / 256, 256, 0, stream>>>(featp, attn_l, attn_r,
                                                            el, er, N);
    hipMemsetAsync(cnt, 0, (size_t)N * 4, stream);
    k_hist<<<(E + 255) / 256, 256, 0, stream>>>(dst, cnt, pos, E);
    k_scan1<<<nb, 256, 0, stream>>>(cnt, bsum, N);
    k_scan2<<<1, 1024, 0, stream>>>(bsum, nb);
    k_scan3<<<nb, 256, 0, stream>>>(cnt, bsum, row, N);
    k_scatter<<<(E + 255) / 256, 256, 0, stream>>>(src, dst, pos, row, esrc, E);
    k_pull<<<((size_t)N * 64 + 255) / 256, 256, 0, stream>>>(esrc, row, cnt, el, er,
                                                             featp, bias, out, N);
}

// Round 8
// 351.426 us; speedup vs baseline: 1.9957x; 1.1593x over previous
//
#include <hip/hip_runtime.h>
#include <math.h>

#define NEG_SLOPE 0.2f

static __device__ __forceinline__ float bf2f(unsigned int hw) {
    return __uint_as_float(hw << 16);
}
static __device__ __forceinline__ unsigned short f2bf(float f) {
    unsigned int u = __float_as_uint(f);
    u += 0x7FFFu + ((u >> 16) & 1u);   // round-to-nearest-even
    return (unsigned short)(u >> 16);
}

// ===========================================================================
// K_A: blocks [0, gemm_blocks) run the fp32 GEMM (feat = h@W.T, packed to
// bf16 featp[n][d][h]); blocks [gemm_blocks, ...) run the CSR histogram
// (2 device-scope int atomics per thread). Independent work, fused so the
// VALU-bound GEMM overlaps the fabric-atomic-latency-bound histogram.
// ===========================================================================
__global__ __launch_bounds__(256, 3) void k_gemm_hist(
    const float* __restrict__ h, const float* __restrict__ W,
    unsigned short* __restrict__ featp, int N,
    const int* __restrict__ dst, int* __restrict__ cnt, int* __restrict__ pos,
    int E, int gemm_blocks)
{
    __shared__ float As[64 * 68];
    __shared__ float Bs[128 * 64];

    if (blockIdx.x >= gemm_blocks) {
        // ---- histogram: pos[e] = rank of edge within its dst segment
        int e = (blockIdx.x - gemm_blocks) * 512 + threadIdx.x;
        if (e < E) pos[e] = atomicAdd(&cnt[dst[e]], 1);
        e += 256;
        if (e < E) pos[e] = atomicAdd(&cnt[dst[e]], 1);
        return;
    }

    // ---- GEMM: 64x128 block tile, 8 rows x 4 heads per thread
    const int tid = threadIdx.x;
    const int rb = blockIdx.x * 64;
    const int tc = tid & 31;
    const int tr = tid >> 5;

    float acc[8][4];
#pragma unroll
    for (int i = 0; i < 8; ++i)
#pragma unroll
        for (int j = 0; j < 4; ++j) acc[i][j] = 0.0f;

    for (int kch = 0; kch < 2; ++kch) {
        if (kch) __syncthreads();
#pragma unroll
        for (int i = 0; i < 4; ++i) {
            int chunk = i * 256 + tid;
            int r = chunk >> 4;
            int kc = (chunk & 15) << 2;
            int row = rb + r;
            float4 v = make_float4(0.f, 0.f, 0.f, 0.f);
            if (row < N) v = *(const float4*)(h + (size_t)row * 128 + kch * 64 + kc);
            *(float4*)(As + r * 68 + kc) = v;
        }
#pragma unroll
        for (int i = 0; i < 8; ++i) {
            int chunk = i * 256 + tid;
            int c = chunk >> 4;
            int kc = (chunk & 15) << 2;
            float4 v = *(const float4*)(W + (size_t)c * 128 + kch * 64 + kc);
            int slot = (kc >> 2) ^ (c & 7);
            *(float4*)(Bs + (c << 6) + (slot << 2)) = v;
        }
        __syncthreads();

#pragma unroll 4
        for (int k4 = 0; k4 < 64; k4 += 4) {
            float4 b[4];
#pragma unroll
            for (int j = 0; j < 4; ++j) {
                int c = tc + 32 * j;
                int slot = (k4 >> 2) ^ (c & 7);
                b[j] = *(const float4*)(Bs + (c << 6) + (slot << 2));
            }
            float4 a[8];
#pragma unroll
            for (int i = 0; i < 8; ++i)
                a[i] = *(const float4*)(As + (tr * 8 + i) * 68 + k4);
#pragma unroll
            for (int i = 0; i < 8; ++i)
#pragma unroll
                for (int j = 0; j < 4; ++j)
                    acc[i][j] += a[i].x * b[j].x + a[i].y * b[j].y +
                                 a[i].z * b[j].z + a[i].w * b[j].w;
        }
    }
#pragma unroll
    for (int i = 0; i < 8; ++i) {
        int row = rb + tr * 8 + i;
        if (row < N) {
            ushort4 pk;
            pk.x = f2bf(acc[i][0]);
            pk.y = f2bf(acc[i][1]);
            pk.z = f2bf(acc[i][2]);
            pk.w = f2bf(acc[i][3]);
            *(ushort4*)(featp + (size_t)row * 128 + tc * 4) = pk;
        }
    }
}

// ===========================================================================
// Scans: row = exclusive_scan(cnt)
// ===========================================================================
__global__ void k_scan1(const int* __restrict__ cnt, int* __restrict__ bsum, int N) {
    __shared__ int sd[256];
    int t = threadIdx.x;
    int i = blockIdx.x * 256 + t;
    sd[t] = (i < N) ? cnt[i] : 0;
    __syncthreads();
    for (int s = 128; s > 0; s >>= 1) {
        if (t < s) sd[t] += sd[t + s];
        __syncthreads();
    }
    if (t == 0) bsum[blockIdx.x] = sd[0];
}

__global__ void k_scan2(int* __restrict__ bsum, int nb) {
    __shared__ int sd[1024];
    int t = threadIdx.x;
    sd[t] = (t < nb) ? bsum[t] : 0;
    __syncthreads();
    for (int off = 1; off < 1024; off <<= 1) {
        int add = (t >= off) ? sd[t - off] : 0;
        __syncthreads();
        sd[t] += add;
        __syncthreads();
    }
    if (t < nb) bsum[t] = (t == 0) ? 0 : sd[t - 1];
}

__global__ void k_scan3(const int* __restrict__ cnt, const int* __restrict__ bsum,
                        int* __restrict__ row, int N) {
    __shared__ int sd[256];
    int t = threadIdx.x;
    int i = blockIdx.x * 256 + t;
    int v = (i < N) ? cnt[i] : 0;
    sd[t] = v;
    __syncthreads();
    for (int off = 1; off < 256; off <<= 1) {
        int add = (t >= off) ? sd[t - off] : 0;
        __syncthreads();
        sd[t] += add;
        __syncthreads();
    }
    if (i < N) row[i] = bsum[blockIdx.x] + sd[t] - v;
}

// ===========================================================================
// K_B: blocks [0, scat_blocks) scatter esrc (plain stores); the rest
// compute el/er from packed bf16 feat. Independent work, fused.
// ===========================================================================
__global__ void k_scatter_elr(const int* __restrict__ src, const int* __restrict__ dst,
                              const int* __restrict__ pos, const int* __restrict__ row,
                              int* __restrict__ esrc, int E, int scat_blocks,
                              const unsigned short* __restrict__ featp,
                              const float* __restrict__ attn_l,
                              const float* __restrict__ attn_r,
                              float* __restrict__ el, float* __restrict__ er, int N) {
    if (blockIdx.x < scat_blocks) {
        int e = blockIdx.x * 512 + threadIdx.x;
        if (e < E) esrc[row[dst[e]] + pos[e]] = src[e];
        e += 256;
        if (e < E) esrc[row[dst[e]] + pos[e]] = src[e];
        return;
    }
    int g = (blockIdx.x - scat_blocks) * 256 + threadIdx.x;
    int node = g >> 5;
    int d = g & 31;
    if (node >= N) return;
    uint2 u = *(const uint2*)(featp + (size_t)node * 128 + d * 4);
    float f0 = bf2f(u.x & 0xffffu);
    float f1 = bf2f(u.x >> 16);
    float f2 = bf2f(u.y & 0xffffu);
    float f3 = bf2f(u.y >> 16);
    float pl0 = f0 * attn_l[d],      pr0 = f0 * attn_r[d];
    float pl1 = f1 * attn_l[32 + d], pr1 = f1 * attn_r[32 + d];
    float pl2 = f2 * attn_l[64 + d], pr2 = f2 * attn_r[64 + d];
    float pl3 = f3 * attn_l[96 + d], pr3 = f3 * attn_r[96 + d];
#pragma unroll
    for (int m = 1; m < 32; m <<= 1) {
        pl0 += __shfl_xor(pl0, m); pr0 += __shfl_xor(pr0, m);
        pl1 += __shfl_xor(pl1, m); pr1 += __shfl_xor(pr1, m);
        pl2 += __shfl_xor(pl2, m); pr2 += __shfl_xor(pr2, m);
        pl3 += __shfl_xor(pl3, m); pr3 += __shfl_xor(pr3, m);
    }
    if (d == 0) {
        *(float4*)(el + (size_t)node * 4) = make_float4(pl0, pl1, pl2, pl3);
        *(float4*)(er + (size_t)node * 4) = make_float4(pr0, pr1, pr2, pr3);
    }
}

// ===========================================================================
// Pull, phase-split: one wave per dst node, 64-edge chunks.
// Phase A (edge-parallel): lane i owns edge i -> 1 el-gather + 4 exp PER EDGE.
// Phase B: WAVE-UNIFORM trip count (ii even, i = ii + half) so every __shfl
// executes with all 64 lanes active — shfl from an exec-masked-off lane
// returns 0 on CDNA, which silently dropped edges at high-degree nodes
// (the R6 absmax failure). Phantom edge i==m broadcasts lane m's zero
// a-values -> contributes exactly 0. No atomics anywhere.
// ===========================================================================
__global__ __launch_bounds__(256) void k_pull(const int* __restrict__ esrc,
                                              const int* __restrict__ row,
                                              const int* __restrict__ cnt,
                                              const float* __restrict__ el,
                                              const float* __restrict__ er,
                                              const unsigned short* __restrict__ featp,
                                              const float* __restrict__ bias,
                                              float* __restrict__ out, int N) {
    int wave = (int)((blockIdx.x * (size_t)blockDim.x + threadIdx.x) >> 6);
    if (wave >= N) return;
    int lane = threadIdx.x & 63;
    int half = lane >> 5;
    int d = lane & 31;
    int start = row[wave];
    int deg = cnt[wave];
    float4 r4 = *(const float4*)(er + 4 * (size_t)wave);

    float acc0 = 0.f, acc1 = 0.f, acc2 = 0.f, acc3 = 0.f;
    float dn0 = 0.f, dn1 = 0.f, dn2 = 0.f, dn3 = 0.f;

    for (int base = 0; base < deg; base += 64) {
        int m = deg - base;
        if (m > 64) m = 64;
        // Phase A: lane owns edge base+lane
        int s_mine = 0;
        float a0 = 0.f, a1 = 0.f, a2 = 0.f, a3 = 0.f;
        if (lane < m) {
            s_mine = esrc[start + base + lane];
            float4 l4 = *(const float4*)(el + 4 * (size_t)s_mine);
            float v0 = l4.x + r4.x; v0 = v0 > 0.f ? v0 : NEG_SLOPE * v0;
            float v1 = l4.y + r4.y; v1 = v1 > 0.f ? v1 : NEG_SLOPE * v1;
            float v2 = l4.z + r4.z; v2 = v2 > 0.f ? v2 : NEG_SLOPE * v2;
            float v3 = l4.w + r4.w; v3 = v3 > 0.f ? v3 : NEG_SLOPE * v3;
            a0 = __expf(v0); a1 = __expf(v1); a2 = __expf(v2); a3 = __expf(v3);
            dn0 += a0; dn1 += a1; dn2 += a2; dn3 += a3;
        }
        // Phase B: half 0 takes edge ii, half 1 takes edge ii+1; uniform flow
        for (int ii = 0; ii < m; ii += 2) {
            int i = ii + half;             // <= 63 always (m <= 64, ii even)
            int sj   = __shfl(s_mine, i);
            float b0 = __shfl(a0, i);
            float b1 = __shfl(a1, i);
            float b2 = __shfl(a2, i);
            float b3 = __shfl(a3, i);
            uint2 u = *(const uint2*)(featp + (size_t)sj * 128 + d * 4);
            float f0 = bf2f(u.x & 0xffffu);
            float f1 = bf2f(u.x >> 16);
            float f2 = bf2f(u.y & 0xffffu);
            float f3 = bf2f(u.y >> 16);
            acc0 += b0 * f0; acc1 += b1 * f1; acc2 += b2 * f2; acc3 += b3 * f3;
        }
    }
    // acc: lanes d and d+32 hold even/odd-edge partials for dim d
    acc0 += __shfl_xor(acc0, 32); acc1 += __shfl_xor(acc1, 32);
    acc2 += __shfl_xor(acc2, 32); acc3 += __shfl_xor(acc3, 32);
    // dn: per-owner-lane partials across all 64 lanes -> full tree reduce
#pragma unroll
    for (int m = 1; m < 64; m <<= 1) {
        dn0 += __shfl_xor(dn0, m); dn1 += __shfl_xor(dn1, m);
        dn2 += __shfl_xor(dn2, m); dn3 += __shfl_xor(dn3, m);
    }
    if (half == 0) {
        float msum = 0.f;
        if (dn0 > 0.f)
            msum = acc0 / dn0 + acc1 / dn1 + acc2 / dn2 + acc3 / dn3;
        float b = 0.25f * (bias[d] + bias[32 + d] + bias[64 + d] + bias[96 + d]);
        out[(size_t)wave * 32 + d] = 0.25f * msum + b;
    }
}

// ===========================================================================
extern "C" void kernel_launch(void* const* d_in, const int* in_sizes, int n_in,
                              void* d_out, int out_size, void* d_ws, size_t ws_size,
                              hipStream_t stream) {
    const float* h      = (const float*)d_in[0];
    const int*   src    = (const int*)d_in[1];
    const int*   dst    = (const int*)d_in[2];
    const float* W      = (const float*)d_in[4];
    const float* attn_l = (const float*)d_in[5];
    const float* attn_r = (const float*)d_in[6];
    const float* bias   = (const float*)d_in[7];
    float* out = (float*)d_out;

    const int N = in_sizes[0] / 128;
    const int E = in_sizes[1];

    // ws layout: el [N,4] f32 | er [N,4] f32 | featp [N,128] bf16 |
    //            cnt [N] | row [N] | bsum [1024] | pos [E] | esrc [E]
    float* el = (float*)d_ws;
    float* er = el + (size_t)N * 4;
    unsigned short* featp = (unsigned short*)(er + (size_t)N * 4);
    int* cnt  = (int*)(featp + (size_t)N * 128);
    int* row  = cnt + N;
    int* bsum = row + N;
    int* pos  = bsum + 1024;
    int* esrc = pos + E;
    int nb = (N + 255) / 256;  // <= 1024 for N <= 262144

    hipMemsetAsync(cnt, 0, (size_t)N * 4, stream);

    int gemm_blocks = (N + 63) / 64;
    int hist_blocks = (E + 511) / 512;
    k_gemm_hist<<<gemm_blocks + hist_blocks, 256, 0, stream>>>(
        h, W, featp, N, dst, cnt, pos, E, gemm_blocks);

    k_scan1<<<nb, 256, 0, stream>>>(cnt, bsum, N);
    k_scan2<<<1, 1024, 0, stream>>>(bsum, nb);
    k_scan3<<<nb, 256, 0, stream>>>(cnt, bsum, row, N);

    int scat_blocks = (E + 511) / 512;
    int elr_blocks = ((size_t)N * 32 + 255) / 256;
    k_scatter_elr<<<scat_blocks + elr_blocks, 256, 0, stream>>>(
        src, dst, pos, row, esrc, E, scat_blocks,
        featp, attn_l, attn_r, el, er, N);

    k_pull<<<((size_t)N * 64 + 255) / 256, 256, 0, stream>>>(esrc, row, cnt, el, er,
                                                             featp, bias, out, N);
}